// Round 1
// 531.929 us; speedup vs baseline: 1.1685x; 1.1685x over previous
//
#include <hip/hip_runtime.h>
#include <hip/hip_bf16.h>
#include <stdint.h>

typedef __hip_bfloat16 bf16;
typedef __attribute__((ext_vector_type(8))) short bf16x8;   // 8 bf16 = 4 VGPRs
typedef __attribute__((ext_vector_type(4))) float f32x4;

static constexpr int Mtot = 8192;   // B*T
static constexpr int Ktot = 4096;   // DIN
static constexpr int Ntot = 4096;   // DOUT
static constexpr int BM = 256, BN = 256, BK = 64;
static constexpr int NKT = Ktot / BK;           // 64 K-tiles
static constexpr int CAST_BLOCKS = (Mtot * Ktot / 8) / 256;  // 16384
static constexpr int PREP_BLOCKS = (Ntot * Ktot / 8) / 256;  // 2048

__device__ __forceinline__ void gl_lds16(const void* g, void* l) {
  __builtin_amdgcn_global_load_lds(
      (const __attribute__((address_space(1))) void*)g,
      (__attribute__((address_space(3))) void*)l,
      16, 0, 0);
}

__device__ __forceinline__ uint32_t bf16pair(float a, float b) {
  __hip_bfloat16 ha = __float2bfloat16(a), hb = __float2bfloat16(b);
  uint16_t ia, ib;
  __builtin_memcpy(&ia, &ha, 2);
  __builtin_memcpy(&ib, &hb, 2);
  return (uint32_t)ia | ((uint32_t)ib << 16);
}

// ---------- fused prep: cast x -> bf16  AND  W_eff -> bf16 ----------
__global__ __launch_bounds__(256) void prep_kernel(const float* __restrict__ x,
                                                   bf16* __restrict__ xb,
                                                   const float* __restrict__ W,
                                                   const float* __restrict__ U,
                                                   const float* __restrict__ S,
                                                   const float* __restrict__ Vh,
                                                   const float* __restrict__ P,
                                                   const float* __restrict__ v,
                                                   bf16* __restrict__ Wp) {
  const int bid = blockIdx.x;
  if (bid < CAST_BLOCKS) {
    size_t gid = (size_t)bid * 256 + threadIdx.x;
    size_t d0 = gid * 8;
    const float4 a = ((const float4*)(x + d0))[0];
    const float4 b = ((const float4*)(x + d0))[1];
    uint4 pk;
    pk.x = bf16pair(a.x, a.y);
    pk.y = bf16pair(a.z, a.w);
    pk.z = bf16pair(b.x, b.y);
    pk.w = bf16pair(b.z, b.w);
    ((uint4*)(xb + d0))[0] = pk;
  } else {
    float R0 = 0.f, R1 = 0.f, R2 = 0.f, R3 = 0.f;
#pragma unroll
    for (int u = 0; u < 16; ++u) {
      float vu = v[u];
      R0 += vu * P[u * 4 + 0];
      R1 += vu * P[u * 4 + 1];
      R2 += vu * P[u * 4 + 2];
      R3 += vu * P[u * 4 + 3];
    }
    float SR00 = S[0] * R0 + S[1] * R2, SR01 = S[0] * R1 + S[1] * R3;
    float SR10 = S[2] * R0 + S[3] * R2, SR11 = S[2] * R1 + S[3] * R3;

    int gid = (bid - CAST_BLOCKS) * 256 + threadIdx.x;
    int o = gid >> 9;
    int d0 = (gid & 511) << 3;
    float u0 = U[o * 2 + 0], u1 = U[o * 2 + 1];
    float M0 = u0 * SR00 + u1 * SR10;
    float M1 = u0 * SR01 + u1 * SR11;

    const float* wrow = W + (size_t)o * Ktot + d0;
    const float4 w0 = ((const float4*)wrow)[0];
    const float4 w1 = ((const float4*)wrow)[1];
    const float4 a0 = ((const float4*)(Vh + d0))[0];
    const float4 a1 = ((const float4*)(Vh + d0))[1];
    const float4 b0 = ((const float4*)(Vh + Ktot + d0))[0];
    const float4 b1 = ((const float4*)(Vh + Ktot + d0))[1];
    float val[8];
    val[0] = w0.x + M0 * a0.x + M1 * b0.x;
    val[1] = w0.y + M0 * a0.y + M1 * b0.y;
    val[2] = w0.z + M0 * a0.z + M1 * b0.z;
    val[3] = w0.w + M0 * a0.w + M1 * b0.w;
    val[4] = w1.x + M0 * a1.x + M1 * b1.x;
    val[5] = w1.y + M0 * a1.y + M1 * b1.y;
    val[6] = w1.z + M0 * a1.z + M1 * b1.z;
    val[7] = w1.w + M0 * a1.w + M1 * b1.w;
    uint4 pk;
    pk.x = bf16pair(val[0], val[1]);
    pk.y = bf16pair(val[2], val[3]);
    pk.z = bf16pair(val[4], val[5]);
    pk.w = bf16pair(val[6], val[7]);
    ((uint4*)(Wp + (size_t)o * Ktot + d0))[0] = pk;
  }
}

// ---------- main GEMM: 256x256 tile, BK=64, 8 waves, 8-phase schedule ----------
// T2: LDS XOR swizzle col ^= ((row&7)<<3) elems, applied on BOTH the global
//     source of global_load_lds (linear LDS dest) and the ds_read address.
// T3+T4: 8 phases / 2 K-tiles, counted vmcnt(4)/vmcnt(6) at phases 4/8 only.
// T5: setprio(1) around each 16-MFMA cluster.
// T1: bijective XCD swizzle (512 wg, 512%8==0).

#define SCHEDB __builtin_amdgcn_sched_barrier(0)
#define BAR do { SCHEDB; __builtin_amdgcn_s_barrier(); SCHEDB; } while (0)
#define LG0 do { asm volatile("s_waitcnt lgkmcnt(0)" ::: "memory"); SCHEDB; } while (0)
#define LG8 do { asm volatile("s_waitcnt lgkmcnt(8)" ::: "memory"); } while (0)
#define WVM(n) do { asm volatile("s_waitcnt vmcnt(" #n ")" ::: "memory"); } while (0)

__global__ __launch_bounds__(512, 2) void gemm_kernel(const bf16* __restrict__ A,
                                                      const bf16* __restrict__ Bt,
                                                      const float* __restrict__ bias,
                                                      float* __restrict__ out) {
  __shared__ __align__(16) bf16 As[2][BM * BK];   // 2 x 32 KiB
  __shared__ __align__(16) bf16 Bs[2][BN * BK];   // 2 x 32 KiB

  const int tid = (int)threadIdx.x;
  const int lane = tid & 63;
  const int w = tid >> 6;                 // wave 0..7
  const int wr = w >> 2;                  // 0..1 -> 128 M-rows
  const int wc = w & 3;                   // 0..3 -> 64 N-cols

  int bid = (int)blockIdx.x;
  bid = (bid & 7) * 64 + (bid >> 3);      // XCD swizzle: 512 wg / 8 XCDs
  const int m0 = (bid >> 4) * BM;         // 32 m-tiles
  const int n0 = (bid & 15) * BN;         // 16 n-tiles

  // ---- staging addressing: wave w covers 16 rows of each 128-row half ----
  // physical LDS is linear (base + lane*16); global source col is
  // pre-swizzled so logical[row][col ^ ((row&7)<<3)] lands linearly.
  const int l8 = lane >> 3;                       // 0..7 row within 8-row issue
  const int swcol = ((lane & 7) ^ l8) << 3;       // element offset (row&7 == l8)
  const bf16* gA = A + (size_t)(m0 + w * 16 + l8) * Ktot + swcol;
  const bf16* gB = Bt + (size_t)(n0 + w * 16 + l8) * Ktot + swcol;

  // ---- compute-side lane addressing (ds_read_b128, swizzled) ----
  const int fm = lane & 15;
  const int q = lane >> 4;                 // k-chunk 0..3
  const int rx = (fm & 7) << 4;            // byte xor (row&7 == fm&7 for all frags)
  const int clo = (q * 16) ^ (rx & 48);
  const int aoff0 = (wr * 128 + fm) * 128 + clo + (rx & 64);        // ks=0
  const int aoff1 = (wr * 128 + fm) * 128 + clo + (64 ^ (rx & 64)); // ks=1
  const int boff0 = (wc * 64 + fm) * 128 + clo + (rx & 64);
  const int boff1 = (wc * 64 + fm) * 128 + clo + (64 ^ (rx & 64));

#define STA(BUF, half, kt) do { \
    const bf16* _g = gA + (size_t)((half) * 128) * Ktot + (kt) * 64; \
    char* _l = (char*)(&As[BUF][0]) + (half) * 16384 + w * 2048; \
    gl_lds16(_g, _l); \
    gl_lds16(_g + (size_t)8 * Ktot, _l + 1024); \
  } while (0)
#define STB(BUF, half, kt) do { \
    const bf16* _g = gB + (size_t)((half) * 128) * Ktot + (kt) * 64; \
    char* _l = (char*)(&Bs[BUF][0]) + (half) * 16384 + w * 2048; \
    gl_lds16(_g, _l); \
    gl_lds16(_g + (size_t)8 * Ktot, _l + 1024); \
  } while (0)
// half-tiles: 0 = A rows 0-127, 1 = A rows 128-255, 2 = B 0-127, 3 = B 128-255
#define STAGE_H(BUF, h, kt) do { \
    if ((h) == 0) STA(BUF, 0, kt); else if ((h) == 1) STA(BUF, 1, kt); \
    else if ((h) == 2) STB(BUF, 0, kt); else STB(BUF, 1, kt); } while (0)

#define RD_A(dst, BUF, mh) do { \
    const char* _p = (const char*)(&As[BUF][0]) + (mh) * 8192; \
    _Pragma("unroll") for (int _i = 0; _i < 4; ++_i) { \
      dst[_i][0] = *(const bf16x8*)(_p + _i * 2048 + aoff0); \
      dst[_i][1] = *(const bf16x8*)(_p + _i * 2048 + aoff1); \
    } } while (0)
#define RD_B(dst, BUF, nh) do { \
    const char* _p = (const char*)(&Bs[BUF][0]) + (nh) * 4096; \
    _Pragma("unroll") for (int _j = 0; _j < 2; ++_j) { \
      dst[_j][0] = *(const bf16x8*)(_p + _j * 2048 + boff0); \
      dst[_j][1] = *(const bf16x8*)(_p + _j * 2048 + boff1); \
    } } while (0)

#define MFMA_Q(AV, BV, MH, NH) do { \
    __builtin_amdgcn_s_setprio(1); \
    _Pragma("unroll") for (int _i = 0; _i < 4; ++_i) \
    _Pragma("unroll") for (int _j = 0; _j < 2; ++_j) { \
      acc[(MH) * 4 + _i][(NH) * 2 + _j] = __builtin_amdgcn_mfma_f32_16x16x32_bf16( \
          AV[_i][0], BV[_j][0], acc[(MH) * 4 + _i][(NH) * 2 + _j], 0, 0, 0); \
      acc[(MH) * 4 + _i][(NH) * 2 + _j] = __builtin_amdgcn_mfma_f32_16x16x32_bf16( \
          AV[_i][1], BV[_j][1], acc[(MH) * 4 + _i][(NH) * 2 + _j], 0, 0, 0); \
    } \
    __builtin_amdgcn_s_setprio(0); \
  } while (0)

  f32x4 acc[8][4];
#pragma unroll
  for (int i = 0; i < 8; ++i)
#pragma unroll
    for (int j = 0; j < 4; ++j) acc[i][j] = {0.f, 0.f, 0.f, 0.f};

  bf16x8 a[4][2], b0[2][2], b1[2][2];

  // ---- prologue: K-tile 0 fully, then 3 half-tiles of K-tile 1 ----
  STAGE_H(0, 0, 0); STAGE_H(0, 1, 0); STAGE_H(0, 2, 0); STAGE_H(0, 3, 0);
  STAGE_H(1, 2, 1); STAGE_H(1, 3, 1); STAGE_H(1, 0, 1);
  WVM(6);   // K-tile 0 (oldest 8 loads) resident; 6 in flight
  BAR;

  // steady state entry invariant: buf(k0) resident; H(k1,{2,3,0}) in flight.
  for (int it = 0; it < 31; ++it) {
    const int k1 = 2 * it + 1;
    const int k2 = 2 * it + 2;
    const int k3 = 2 * it + 3;
    // p1: quad (0,0)
    RD_A(a, 0, 0); RD_B(b0, 0, 0); STAGE_H(1, 1, k1); LG8;
    BAR; LG0; MFMA_Q(a, b0, 0, 0); BAR;
    // p2: quad (0,1)
    RD_B(b1, 0, 1);
    BAR; LG0; MFMA_Q(a, b1, 0, 1); BAR;
    // p3: quad (1,0)  (B-halves of buf0 fully read after p2 -> stage them)
    RD_A(a, 0, 1); STAGE_H(0, 2, k2);
    BAR; LG0; MFMA_Q(a, b0, 1, 0); BAR;
    // p4: quad (1,1); ensure K-tile k1 resident before p5
    STAGE_H(0, 3, k2);
    BAR; MFMA_Q(a, b1, 1, 1); SCHEDB; WVM(4); BAR;
    // p5: quad (0,0) on buf1  (A-halves of buf0 fully read after p3)
    RD_A(a, 1, 0); RD_B(b0, 1, 0); STAGE_H(0, 0, k2); LG8;
    BAR; LG0; MFMA_Q(a, b0, 0, 0); BAR;
    // p6: quad (0,1)
    RD_B(b1, 1, 1); STAGE_H(0, 1, k2);
    BAR; LG0; MFMA_Q(a, b1, 0, 1); BAR;
    // p7: quad (1,0)  (B-halves of buf1 fully read after p6)
    RD_A(a, 1, 1); STAGE_H(1, 2, k3);
    BAR; LG0; MFMA_Q(a, b0, 1, 0); BAR;
    // p8: quad (1,1); ensure K-tile k2 resident before next p1
    STAGE_H(1, 3, k3); STAGE_H(1, 0, k3);
    BAR; MFMA_Q(a, b1, 1, 1); SCHEDB; WVM(6); BAR;
  }

  // ---- tail: k0 = 62 (buf0), k1 = 63 (buf1), no further prefetch ----
  RD_A(a, 0, 0); RD_B(b0, 0, 0); STAGE_H(1, 1, 63); LG8;
  BAR; LG0; MFMA_Q(a, b0, 0, 0); BAR;
  RD_B(b1, 0, 1);
  BAR; LG0; MFMA_Q(a, b1, 0, 1); BAR;
  RD_A(a, 0, 1);
  BAR; LG0; MFMA_Q(a, b0, 1, 0); BAR;
  BAR; MFMA_Q(a, b1, 1, 1); SCHEDB; WVM(0); BAR;
  RD_A(a, 1, 0); RD_B(b0, 1, 0);
  BAR; LG0; MFMA_Q(a, b0, 0, 0); BAR;
  RD_B(b1, 1, 1);
  BAR; LG0; MFMA_Q(a, b1, 0, 1); BAR;
  RD_A(a, 1, 1);
  BAR; LG0; MFMA_Q(a, b0, 1, 0); BAR;
  MFMA_Q(a, b1, 1, 1);

  // ---- epilogue: C/D layout col = lane&15 (N), row = (lane>>4)*4 + reg (M) ----
#pragma unroll
  for (int jb = 0; jb < 4; ++jb) {
    const int gn = n0 + wc * 64 + jb * 16 + fm;
    const float bj = bias[gn];
#pragma unroll
    for (int ia = 0; ia < 8; ++ia) {
      float* o = out + (size_t)(m0 + wr * 128 + ia * 16 + q * 4) * Ntot + gn;
#pragma unroll
      for (int r = 0; r < 4; ++r) o[(size_t)r * Ntot] = acc[ia][jb][r] + bj;
    }
  }

#undef STA
#undef STB
#undef STAGE_H
#undef RD_A
#undef RD_B
#undef MFMA_Q
}

extern "C" void kernel_launch(void* const* d_in, const int* in_sizes, int n_in,
                              void* d_out, int out_size, void* d_ws, size_t ws_size,
                              hipStream_t stream) {
  const float* x  = (const float*)d_in[0];
  const float* W  = (const float*)d_in[1];
  const float* b  = (const float*)d_in[2];
  const float* U  = (const float*)d_in[3];
  const float* S  = (const float*)d_in[4];
  const float* Vh = (const float*)d_in[5];
  const float* P  = (const float*)d_in[6];
  const float* v  = (const float*)d_in[7];
  float* out = (float*)d_out;

  bf16* xb = (bf16*)d_ws;                                    // 67,108,864 B
  bf16* Wp = (bf16*)((char*)d_ws + (size_t)Mtot * Ktot * 2); // +33,554,432 B

  prep_kernel<<<CAST_BLOCKS + PREP_BLOCKS, 256, 0, stream>>>(x, xb, W, U, S, Vh, P, v, Wp);

  dim3 grid(Mtot / BM * (Ntot / BN));  // 512
  gemm_kernel<<<grid, 512, 0, stream>>>(xb, Wp, b, out);
}

// Round 2
// 515.492 us; speedup vs baseline: 1.2058x; 1.0319x over previous
//
#include <hip/hip_runtime.h>
#include <hip/hip_bf16.h>
#include <stdint.h>

typedef __hip_bfloat16 bf16;
typedef __attribute__((ext_vector_type(8))) short bf16x8;   // 8 bf16 = 4 VGPRs
typedef __attribute__((ext_vector_type(4))) float f32x4;

static constexpr int Mtot = 8192;   // B*T
static constexpr int Ktot = 4096;   // DIN
static constexpr int Ntot = 4096;   // DOUT
static constexpr int BM = 256, BN = 256, BK = 64;
static constexpr int NKT = Ktot / BK;           // 64 K-tiles
static constexpr int CAST_BLOCKS = (Mtot * Ktot / 8) / 256;  // 16384
static constexpr int PREP_BLOCKS = (Ntot * Ktot / 8) / 256;  // 2048

__device__ __forceinline__ void gl_lds16(const void* g, void* l) {
  __builtin_amdgcn_global_load_lds(
      (const __attribute__((address_space(1))) void*)g,
      (__attribute__((address_space(3))) void*)l,
      16, 0, 0);
}

__device__ __forceinline__ uint32_t bf16pair(float a, float b) {
  __hip_bfloat16 ha = __float2bfloat16(a), hb = __float2bfloat16(b);
  uint16_t ia, ib;
  __builtin_memcpy(&ia, &ha, 2);
  __builtin_memcpy(&ib, &hb, 2);
  return (uint32_t)ia | ((uint32_t)ib << 16);
}

// ---------- fused prep: cast x -> bf16  AND  W_eff -> bf16 ----------
__global__ __launch_bounds__(256) void prep_kernel(const float* __restrict__ x,
                                                   bf16* __restrict__ xb,
                                                   const float* __restrict__ W,
                                                   const float* __restrict__ U,
                                                   const float* __restrict__ S,
                                                   const float* __restrict__ Vh,
                                                   const float* __restrict__ P,
                                                   const float* __restrict__ v,
                                                   bf16* __restrict__ Wp) {
  const int bid = blockIdx.x;
  if (bid < CAST_BLOCKS) {
    size_t gid = (size_t)bid * 256 + threadIdx.x;
    size_t d0 = gid * 8;
    const float4 a = ((const float4*)(x + d0))[0];
    const float4 b = ((const float4*)(x + d0))[1];
    uint4 pk;
    pk.x = bf16pair(a.x, a.y);
    pk.y = bf16pair(a.z, a.w);
    pk.z = bf16pair(b.x, b.y);
    pk.w = bf16pair(b.z, b.w);
    ((uint4*)(xb + d0))[0] = pk;
  } else {
    float R0 = 0.f, R1 = 0.f, R2 = 0.f, R3 = 0.f;
#pragma unroll
    for (int u = 0; u < 16; ++u) {
      float vu = v[u];
      R0 += vu * P[u * 4 + 0];
      R1 += vu * P[u * 4 + 1];
      R2 += vu * P[u * 4 + 2];
      R3 += vu * P[u * 4 + 3];
    }
    float SR00 = S[0] * R0 + S[1] * R2, SR01 = S[0] * R1 + S[1] * R3;
    float SR10 = S[2] * R0 + S[3] * R2, SR11 = S[2] * R1 + S[3] * R3;

    int gid = (bid - CAST_BLOCKS) * 256 + threadIdx.x;
    int o = gid >> 9;
    int d0 = (gid & 511) << 3;
    float u0 = U[o * 2 + 0], u1 = U[o * 2 + 1];
    float M0 = u0 * SR00 + u1 * SR10;
    float M1 = u0 * SR01 + u1 * SR11;

    const float* wrow = W + (size_t)o * Ktot + d0;
    const float4 w0 = ((const float4*)wrow)[0];
    const float4 w1 = ((const float4*)wrow)[1];
    const float4 a0 = ((const float4*)(Vh + d0))[0];
    const float4 a1 = ((const float4*)(Vh + d0))[1];
    const float4 b0 = ((const float4*)(Vh + Ktot + d0))[0];
    const float4 b1 = ((const float4*)(Vh + Ktot + d0))[1];
    float val[8];
    val[0] = w0.x + M0 * a0.x + M1 * b0.x;
    val[1] = w0.y + M0 * a0.y + M1 * b0.y;
    val[2] = w0.z + M0 * a0.z + M1 * b0.z;
    val[3] = w0.w + M0 * a0.w + M1 * b0.w;
    val[4] = w1.x + M0 * a1.x + M1 * b1.x;
    val[5] = w1.y + M0 * a1.y + M1 * b1.y;
    val[6] = w1.z + M0 * a1.z + M1 * b1.z;
    val[7] = w1.w + M0 * a1.w + M1 * b1.w;
    uint4 pk;
    pk.x = bf16pair(val[0], val[1]);
    pk.y = bf16pair(val[2], val[3]);
    pk.z = bf16pair(val[4], val[5]);
    pk.w = bf16pair(val[6], val[7]);
    ((uint4*)(Wp + (size_t)o * Ktot + d0))[0] = pk;
  }
}

// ---------- main GEMM: 256x256 tile, BK=64, 8 waves, 8-phase schedule ----------
// T2: LDS XOR swizzle col ^= ((row&7)<<3) elems, applied on BOTH the global
//     source of global_load_lds (linear LDS dest) and the ds_read address.
// T3+T4: 8 phases / 2 K-tiles, counted vmcnt(4)/vmcnt(6) at phases 4/8 only.
// T5: setprio(1) around each 16-MFMA cluster.
// T1': XCD-cooperative mapping. bid%8 = XCD (HW round-robin). Each XCD's 32
//      concurrently-resident CUs form a 4 Mtile x 8 Ntile block, so the
//      per-K-tile working set is (4+8)*32KB = 384 KB << 4 MiB XCD-L2.
//      A slices hit L2 8x, B slices 4x -> supply moves from LLC (~7 TB/s
//      congested) to XCD-local L2 (34.5 TB/s aggregate). Bijective over 512.

#define SCHEDB __builtin_amdgcn_sched_barrier(0)
#define BAR do { SCHEDB; __builtin_amdgcn_s_barrier(); SCHEDB; } while (0)
#define LG0 do { asm volatile("s_waitcnt lgkmcnt(0)" ::: "memory"); SCHEDB; } while (0)
#define LG8 do { asm volatile("s_waitcnt lgkmcnt(8)" ::: "memory"); } while (0)
#define WVM(n) do { asm volatile("s_waitcnt vmcnt(" #n ")" ::: "memory"); } while (0)

__global__ __launch_bounds__(512, 2) void gemm_kernel(const bf16* __restrict__ A,
                                                      const bf16* __restrict__ Bt,
                                                      const float* __restrict__ bias,
                                                      float* __restrict__ out) {
  __shared__ __align__(16) bf16 As[2][BM * BK];   // 2 x 32 KiB
  __shared__ __align__(16) bf16 Bs[2][BN * BK];   // 2 x 32 KiB

  const int tid = (int)threadIdx.x;
  const int lane = tid & 63;
  const int w = tid >> 6;                 // wave 0..7
  const int wr = w >> 2;                  // 0..1 -> 128 M-rows
  const int wc = w & 3;                   // 0..3 -> 64 N-cols

  // ---- XCD-cooperative tile mapping (bijective over 512 wgs) ----
  const int bid = (int)blockIdx.x;        // 0..511
  const int xcd = bid & 7;                // HW: XCC_ID = bid % 8
  const int ord = bid >> 3;               // arrival order within XCD, 0..63
  const int rnd = ord >> 5;               // round 0..1 (1 wg/CU, 32 CUs/XCD)
  const int slt = ord & 31;               // slot within round
  const int mt = rnd * 16 + (xcd >> 1) * 4 + (slt >> 3);  // 0..31
  const int nt = (xcd & 1) * 8 + (slt & 7);               // 0..15
  const int m0 = mt * BM;
  const int n0 = nt * BN;

  // ---- staging addressing: wave w covers 16 rows of each 128-row half ----
  // physical LDS is linear (base + lane*16); global source col is
  // pre-swizzled so logical[row][col ^ ((row&7)<<3)] lands linearly.
  const int l8 = lane >> 3;                       // 0..7 row within 8-row issue
  const int swcol = ((lane & 7) ^ l8) << 3;       // element offset (row&7 == l8)
  const bf16* gA = A + (size_t)(m0 + w * 16 + l8) * Ktot + swcol;
  const bf16* gB = Bt + (size_t)(n0 + w * 16 + l8) * Ktot + swcol;

  // ---- compute-side lane addressing (ds_read_b128, swizzled) ----
  const int fm = lane & 15;
  const int q = lane >> 4;                 // k-chunk 0..3
  const int rx = (fm & 7) << 4;            // byte xor (row&7 == fm&7 for all frags)
  const int clo = (q * 16) ^ (rx & 48);
  const int aoff0 = (wr * 128 + fm) * 128 + clo + (rx & 64);        // ks=0
  const int aoff1 = (wr * 128 + fm) * 128 + clo + (64 ^ (rx & 64)); // ks=1
  const int boff0 = (wc * 64 + fm) * 128 + clo + (rx & 64);
  const int boff1 = (wc * 64 + fm) * 128 + clo + (64 ^ (rx & 64));

#define STA(BUF, half, kt) do { \
    const bf16* _g = gA + (size_t)((half) * 128) * Ktot + (kt) * 64; \
    char* _l = (char*)(&As[BUF][0]) + (half) * 16384 + w * 2048; \
    gl_lds16(_g, _l); \
    gl_lds16(_g + (size_t)8 * Ktot, _l + 1024); \
  } while (0)
#define STB(BUF, half, kt) do { \
    const bf16* _g = gB + (size_t)((half) * 128) * Ktot + (kt) * 64; \
    char* _l = (char*)(&Bs[BUF][0]) + (half) * 16384 + w * 2048; \
    gl_lds16(_g, _l); \
    gl_lds16(_g + (size_t)8 * Ktot, _l + 1024); \
  } while (0)
// half-tiles: 0 = A rows 0-127, 1 = A rows 128-255, 2 = B 0-127, 3 = B 128-255
#define STAGE_H(BUF, h, kt) do { \
    if ((h) == 0) STA(BUF, 0, kt); else if ((h) == 1) STA(BUF, 1, kt); \
    else if ((h) == 2) STB(BUF, 0, kt); else STB(BUF, 1, kt); } while (0)

#define RD_A(dst, BUF, mh) do { \
    const char* _p = (const char*)(&As[BUF][0]) + (mh) * 8192; \
    _Pragma("unroll") for (int _i = 0; _i < 4; ++_i) { \
      dst[_i][0] = *(const bf16x8*)(_p + _i * 2048 + aoff0); \
      dst[_i][1] = *(const bf16x8*)(_p + _i * 2048 + aoff1); \
    } } while (0)
#define RD_B(dst, BUF, nh) do { \
    const char* _p = (const char*)(&Bs[BUF][0]) + (nh) * 4096; \
    _Pragma("unroll") for (int _j = 0; _j < 2; ++_j) { \
      dst[_j][0] = *(const bf16x8*)(_p + _j * 2048 + boff0); \
      dst[_j][1] = *(const bf16x8*)(_p + _j * 2048 + boff1); \
    } } while (0)

#define MFMA_Q(AV, BV, MH, NH) do { \
    __builtin_amdgcn_s_setprio(1); \
    _Pragma("unroll") for (int _i = 0; _i < 4; ++_i) \
    _Pragma("unroll") for (int _j = 0; _j < 2; ++_j) { \
      acc[(MH) * 4 + _i][(NH) * 2 + _j] = __builtin_amdgcn_mfma_f32_16x16x32_bf16( \
          AV[_i][0], BV[_j][0], acc[(MH) * 4 + _i][(NH) * 2 + _j], 0, 0, 0); \
      acc[(MH) * 4 + _i][(NH) * 2 + _j] = __builtin_amdgcn_mfma_f32_16x16x32_bf16( \
          AV[_i][1], BV[_j][1], acc[(MH) * 4 + _i][(NH) * 2 + _j], 0, 0, 0); \
    } \
    __builtin_amdgcn_s_setprio(0); \
  } while (0)

  f32x4 acc[8][4];
#pragma unroll
  for (int i = 0; i < 8; ++i)
#pragma unroll
    for (int j = 0; j < 4; ++j) acc[i][j] = {0.f, 0.f, 0.f, 0.f};

  bf16x8 a[4][2], b0[2][2], b1[2][2];

  // ---- prologue: K-tile 0 fully, then 3 half-tiles of K-tile 1 ----
  STAGE_H(0, 0, 0); STAGE_H(0, 1, 0); STAGE_H(0, 2, 0); STAGE_H(0, 3, 0);
  STAGE_H(1, 2, 1); STAGE_H(1, 3, 1); STAGE_H(1, 0, 1);
  WVM(6);   // K-tile 0 (oldest 8 loads) resident; 6 in flight
  BAR;

  // steady state entry invariant: buf(k0) resident; H(k1,{2,3,0}) in flight.
  for (int it = 0; it < 31; ++it) {
    const int k1 = 2 * it + 1;
    const int k2 = 2 * it + 2;
    const int k3 = 2 * it + 3;
    // p1: quad (0,0)
    RD_A(a, 0, 0); RD_B(b0, 0, 0); STAGE_H(1, 1, k1); LG8;
    BAR; LG0; MFMA_Q(a, b0, 0, 0); BAR;
    // p2: quad (0,1)
    RD_B(b1, 0, 1);
    BAR; LG0; MFMA_Q(a, b1, 0, 1); BAR;
    // p3: quad (1,0)  (B-halves of buf0 fully read after p2 -> stage them)
    RD_A(a, 0, 1); STAGE_H(0, 2, k2);
    BAR; LG0; MFMA_Q(a, b0, 1, 0); BAR;
    // p4: quad (1,1); ensure K-tile k1 resident before p5
    STAGE_H(0, 3, k2);
    BAR; MFMA_Q(a, b1, 1, 1); SCHEDB; WVM(4); BAR;
    // p5: quad (0,0) on buf1  (A-halves of buf0 fully read after p3)
    RD_A(a, 1, 0); RD_B(b0, 1, 0); STAGE_H(0, 0, k2); LG8;
    BAR; LG0; MFMA_Q(a, b0, 0, 0); BAR;
    // p6: quad (0,1)
    RD_B(b1, 1, 1); STAGE_H(0, 1, k2);
    BAR; LG0; MFMA_Q(a, b1, 0, 1); BAR;
    // p7: quad (1,0)  (B-halves of buf1 fully read after p6)
    RD_A(a, 1, 1); STAGE_H(1, 2, k3);
    BAR; LG0; MFMA_Q(a, b0, 1, 0); BAR;
    // p8: quad (1,1); ensure K-tile k2 resident before next p1
    STAGE_H(1, 3, k3); STAGE_H(1, 0, k3);
    BAR; MFMA_Q(a, b1, 1, 1); SCHEDB; WVM(6); BAR;
  }

  // ---- tail: k0 = 62 (buf0), k1 = 63 (buf1), no further prefetch ----
  RD_A(a, 0, 0); RD_B(b0, 0, 0); STAGE_H(1, 1, 63); LG8;
  BAR; LG0; MFMA_Q(a, b0, 0, 0); BAR;
  RD_B(b1, 0, 1);
  BAR; LG0; MFMA_Q(a, b1, 0, 1); BAR;
  RD_A(a, 0, 1);
  BAR; LG0; MFMA_Q(a, b0, 1, 0); BAR;
  BAR; MFMA_Q(a, b1, 1, 1); SCHEDB; WVM(0); BAR;
  RD_A(a, 1, 0); RD_B(b0, 1, 0);
  BAR; LG0; MFMA_Q(a, b0, 0, 0); BAR;
  RD_B(b1, 1, 1);
  BAR; LG0; MFMA_Q(a, b1, 0, 1); BAR;
  RD_A(a, 1, 1);
  BAR; LG0; MFMA_Q(a, b0, 1, 0); BAR;
  MFMA_Q(a, b1, 1, 1);

  // ---- epilogue: C/D layout col = lane&15 (N), row = (lane>>4)*4 + reg (M) ----
#pragma unroll
  for (int jb = 0; jb < 4; ++jb) {
    const int gn = n0 + wc * 64 + jb * 16 + fm;
    const float bj = bias[gn];
#pragma unroll
    for (int ia = 0; ia < 8; ++ia) {
      float* o = out + (size_t)(m0 + wr * 128 + ia * 16 + q * 4) * Ntot + gn;
#pragma unroll
      for (int r = 0; r < 4; ++r) o[(size_t)r * Ntot] = acc[ia][jb][r] + bj;
    }
  }

#undef STA
#undef STB
#undef STAGE_H
#undef RD_A
#undef RD_B
#undef MFMA_Q
}

extern "C" void kernel_launch(void* const* d_in, const int* in_sizes, int n_in,
                              void* d_out, int out_size, void* d_ws, size_t ws_size,
                              hipStream_t stream) {
  const float* x  = (const float*)d_in[0];
  const float* W  = (const float*)d_in[1];
  const float* b  = (const float*)d_in[2];
  const float* U  = (const float*)d_in[3];
  const float* S  = (const float*)d_in[4];
  const float* Vh = (const float*)d_in[5];
  const float* P  = (const float*)d_in[6];
  const float* v  = (const float*)d_in[7];
  float* out = (float*)d_out;

  bf16* xb = (bf16*)d_ws;                                    // 67,108,864 B
  bf16* Wp = (bf16*)((char*)d_ws + (size_t)Mtot * Ktot * 2); // +33,554,432 B

  prep_kernel<<<CAST_BLOCKS + PREP_BLOCKS, 256, 0, stream>>>(x, xb, W, U, S, Vh, P, v, Wp);

  dim3 grid(Mtot / BM * (Ntot / BN));  // 512
  gemm_kernel<<<grid, 512, 0, stream>>>(xb, Wp, b, out);
}